// Round 11
// baseline (75.485 us; speedup 1.0000x reference)
//
#include <hip/hip_runtime.h>

// PathSampling: per node, score 32 paths (sum of centrality over masked
// prefix), stable top-8, emit selected masked paths + their edge rows.
//
// Round 11: R10 (NT stores, 2 nodes/wave, half-split gathers) + rank
// DEDUPLICATION across halves: each half ranks only its own node (8
// broadcast ds_read_b128 + 32 compares, was 16 + 64), then one
// __shfl_xor(rank,32) exchange lets both halves store their 16B slice of
// each winner. Score-row LDS deps are same-half only; wsrc is intra-wave
// program-ordered. No barriers anywhere.

#define N_NODE   100000
#define N_PATH   32
#define L_PATH   8
#define K_PATH   8

typedef int   v4i __attribute__((ext_vector_type(4)));
typedef float v4f __attribute__((ext_vector_type(4)));

__global__ __launch_bounds__(256) void path_sampling_kernel(
    const int*   __restrict__ paths,
    const int*   __restrict__ edge_ids,
    const int*   __restrict__ rand_lens,
    const float* __restrict__ centrality,
    int*         __restrict__ out_paths,   // [N_NODE, K_PATH, L_PATH]
    int*         __restrict__ out_edges)   // [N_NODE, K_PATH, L_PATH-1]
{
    __shared__ float ssc[4][2][32];   // per-wave: row 0 = node A, 1 = node B
    __shared__ int   wsrc[4][2][8];   // per-wave winner source path per rank

    const int t    = threadIdx.x;
    const int wv   = t >> 6;                 // wave in block (0..3)
    const int lane = t & 63;
    const int half = lane >> 5;              // 0: elems 0-3, 1: elems 4-7
    const int p    = lane & 31;              // path within node
    const int nA   = blockIdx.x * 8 + wv * 2;  // grid*8 == N_NODE exactly
    const int nB   = nA + 1;

    const size_t rA = (size_t)nA * N_PATH + p;
    const size_t rB = (size_t)nB * N_PATH + p;

    // Coalesced b128 path loads + lens for both nodes, issued together.
    const v4i* P4 = (const v4i*)paths;
    v4i a4 = P4[rA * 2 + half];
    v4i b4 = P4[rB * 2 + half];
    const int lena = rand_lens[rA];
    const int lenb = rand_lens[rB];

    // Mask both nodes, then issue all 8 gathers back-to-back.
    const int jb = half * 4;
    int ma[4] = {a4.x, a4.y, a4.z, a4.w};
    int mb[4] = {b4.x, b4.y, b4.z, b4.w};
    #pragma unroll
    for (int k = 0; k < 4; ++k) { if (jb + k > lena) ma[k] = -1; }
    #pragma unroll
    for (int k = 0; k < 4; ++k) { if (jb + k > lenb) mb[k] = -1; }

    float ca[4], cb[4];
    #pragma unroll
    for (int k = 0; k < 4; ++k) ca[k] = (ma[k] < 0) ? 0.0f : centrality[ma[k]];
    #pragma unroll
    for (int k = 0; k < 4; ++k) cb[k] = (mb[k] < 0) ? 0.0f : centrality[mb[k]];

    // numpy pairwise tree; cross-half combine (fp add is bit-commutative).
    const float psA = (ca[0] + ca[1]) + (ca[2] + ca[3]);
    const float psB = (cb[0] + cb[1]) + (cb[2] + cb[3]);
    const float sA  = psA + __shfl_xor(psA, 32);
    const float sB  = psB + __shfl_xor(psB, 32);

    // Each half publishes its own node's score row (no divergent branch):
    // half0 lane p -> ssc[wv][0][p] = sA ; half1 lane p -> ssc[wv][1][p] = sB.
    const float sOwn = half ? sB : sA;
    ssc[wv][half][p] = sOwn;

    // Rank OWN node only: 8 broadcast b128 reads + 32 stable compares.
    const unsigned ltm = (1u << p) - 1u;     // bit j set iff j < p
    const v4f* myrow = (const v4f*)ssc[wv][half];
    int rk = 0;
    #pragma unroll
    for (int q = 0; q < 8; ++q) {
        const v4f sc = myrow[q];
        #pragma unroll
        for (int e = 0; e < 4; ++e) {
            const int j = q * 4 + e;
            rk += (sc[e] > sOwn) || ((sc[e] == sOwn) && ((ltm >> j) & 1u));
        }
    }
    // Exchange ranks across halves (same p, other node).
    const int rkX   = __shfl_xor(rk, 32);
    const int rankA = half ? rkX : rk;
    const int rankB = half ? rk  : rkX;

    // Winner path stores: NT (write-only output, keep inputs L3-resident).
    if (rankA < K_PATH) {
        const size_t obase = (size_t)nA * K_PATH + rankA;
        v4i m = {ma[0], ma[1], ma[2], ma[3]};
        __builtin_nontemporal_store(m, ((v4i*)out_paths) + obase * 2 + half);
        if (!half) wsrc[wv][0][rankA] = p;   // node A published by half0
    }
    if (rankB < K_PATH) {
        const size_t obase = (size_t)nB * K_PATH + rankB;
        v4i m = {mb[0], mb[1], mb[2], mb[3]};
        __builtin_nontemporal_store(m, ((v4i*)out_paths) + obase * 2 + half);
        if (half) wsrc[wv][1][rankB] = p;    // node B published by half1
    }

    // Cooperative edge copy: 56 dwords per node; loads cached (inputs),
    // stores NT (write-only output). wsrc read is intra-wave program-ordered.
    if (lane < 56) {
        const int r   = lane / 7;            // magic-mul
        const int col = lane - r * 7;
        const int* eA = edge_ids + (size_t)nA * (N_PATH * (L_PATH - 1));
        const int* eB = edge_ids + (size_t)nB * (N_PATH * (L_PATH - 1));
        int* dA = out_edges + (size_t)nA * (K_PATH * (L_PATH - 1));
        int* dB = out_edges + (size_t)nB * (K_PATH * (L_PATH - 1));
        const int s0 = wsrc[wv][0][r];
        const int s1 = wsrc[wv][1][r];
        __builtin_nontemporal_store(eA[s0 * 7 + col], dA + lane);
        __builtin_nontemporal_store(eB[s1 * 7 + col], dB + lane);
    }
}

extern "C" void kernel_launch(void* const* d_in, const int* in_sizes, int n_in,
                              void* d_out, int out_size, void* d_ws, size_t ws_size,
                              hipStream_t stream) {
    const int*   paths      = (const int*)  d_in[0];
    const int*   edge_ids   = (const int*)  d_in[1];
    const int*   rand_lens  = (const int*)  d_in[2];
    const float* centrality = (const float*)d_in[3];
    // d_in[4] is k_path (scalar, known == 8)

    int* out_paths = (int*)d_out;
    int* out_edges = out_paths + (size_t)N_NODE * K_PATH * L_PATH;

    // 4 waves/block x 2 nodes/wave = 8 nodes/block
    const int grid = N_NODE / 8;             // 12500, exact

    path_sampling_kernel<<<grid, 256, 0, stream>>>(
        paths, edge_ids, rand_lens, centrality, out_paths, out_edges);
}

// Round 12
// 73.700 us; speedup vs baseline: 1.0242x; 1.0242x over previous
//
#include <hip/hip_runtime.h>

// PathSampling: per node, score 32 paths (sum of centrality over masked
// prefix), stable top-8, emit selected masked paths + their edge rows.
//
// Round 12: revert to the measured-best kernel (R10). NT stores keep the
// 48 MB write-only outputs out of Infinity Cache so the 217.6 MB input set
// stays L3-resident across graph replays (the only lever that moved time).
// Two nodes per wave, half-split lane mapping (4 gathers/lane, 8 in flight),
// LDS-broadcast rank, cooperative edge copy. R11's rank-dedup reverted
// (75.5 vs 73.8 -- the cross-half shfl dependency cost more than the saved
// DS/VALU ops). Intra-wave LDS only -> no barriers.

#define N_NODE   100000
#define N_PATH   32
#define L_PATH   8
#define K_PATH   8

typedef int   v4i __attribute__((ext_vector_type(4)));
typedef float v4f __attribute__((ext_vector_type(4)));

__global__ __launch_bounds__(256) void path_sampling_kernel(
    const int*   __restrict__ paths,
    const int*   __restrict__ edge_ids,
    const int*   __restrict__ rand_lens,
    const float* __restrict__ centrality,
    int*         __restrict__ out_paths,   // [N_NODE, K_PATH, L_PATH]
    int*         __restrict__ out_edges)   // [N_NODE, K_PATH, L_PATH-1]
{
    __shared__ float ssc[4][2][32];   // per-wave, per-node-slot score row
    __shared__ int   wsrc[4][2][8];   // per-wave winner source path per rank

    const int t    = threadIdx.x;
    const int wv   = t >> 6;                 // wave in block (0..3)
    const int lane = t & 63;
    const int half = lane >> 5;              // 0: elems 0-3, 1: elems 4-7
    const int p    = lane & 31;              // path within node
    const int nA   = blockIdx.x * 8 + wv * 2;  // grid*8 == N_NODE exactly
    const int nB   = nA + 1;

    const size_t rA = (size_t)nA * N_PATH + p;
    const size_t rB = (size_t)nB * N_PATH + p;

    // Coalesced b128 path loads + lens for both nodes, issued together.
    const v4i* P4 = (const v4i*)paths;
    v4i a4 = P4[rA * 2 + half];
    v4i b4 = P4[rB * 2 + half];
    const int lena = rand_lens[rA];
    const int lenb = rand_lens[rB];

    // Mask both nodes, then issue all 8 gathers back-to-back.
    const int jb = half * 4;
    int ma[4] = {a4.x, a4.y, a4.z, a4.w};
    int mb[4] = {b4.x, b4.y, b4.z, b4.w};
    #pragma unroll
    for (int k = 0; k < 4; ++k) { if (jb + k > lena) ma[k] = -1; }
    #pragma unroll
    for (int k = 0; k < 4; ++k) { if (jb + k > lenb) mb[k] = -1; }

    float ca[4], cb[4];
    #pragma unroll
    for (int k = 0; k < 4; ++k) ca[k] = (ma[k] < 0) ? 0.0f : centrality[ma[k]];
    #pragma unroll
    for (int k = 0; k < 4; ++k) cb[k] = (mb[k] < 0) ? 0.0f : centrality[mb[k]];

    // numpy pairwise tree; cross-half combine (fp add is bit-commutative).
    const float psA = (ca[0] + ca[1]) + (ca[2] + ca[3]);
    const float psB = (cb[0] + cb[1]) + (cb[2] + cb[3]);
    const float sA  = psA + __shfl_xor(psA, 32);
    const float sB  = psB + __shfl_xor(psB, 32);

    // Publish both score rows (intra-wave LDS, program-ordered).
    if (!half) { ssc[wv][0][p] = sA; ssc[wv][1][p] = sB; }

    // Stable descending rank for both nodes (ties -> lower index wins).
    const unsigned ltm = (1u << p) - 1u;
    int rkA = 0, rkB = 0;
    #pragma unroll
    for (int q = 0; q < 8; ++q) {
        const v4f qa = ((const v4f*)ssc[wv][0])[q];
        const v4f qb = ((const v4f*)ssc[wv][1])[q];
        #pragma unroll
        for (int e = 0; e < 4; ++e) {
            const int j = q * 4 + e;
            rkA += (qa[e] > sA) || ((qa[e] == sA) && ((ltm >> j) & 1u));
            rkB += (qb[e] > sB) || ((qb[e] == sB) && ((ltm >> j) & 1u));
        }
    }

    // Winner path stores: NT (write-only output, keep inputs L3-resident).
    if (rkA < K_PATH) {
        const size_t obase = (size_t)nA * K_PATH + rkA;
        v4i m = {ma[0], ma[1], ma[2], ma[3]};
        __builtin_nontemporal_store(m, ((v4i*)out_paths) + obase * 2 + half);
        if (!half) wsrc[wv][0][rkA] = p;
    }
    if (rkB < K_PATH) {
        const size_t obase = (size_t)nB * K_PATH + rkB;
        v4i m = {mb[0], mb[1], mb[2], mb[3]};
        __builtin_nontemporal_store(m, ((v4i*)out_paths) + obase * 2 + half);
        if (!half) wsrc[wv][1][rkB] = p;
    }

    // Cooperative edge copy: 56 dwords per node; loads cached (inputs),
    // stores NT (write-only output).
    if (lane < 56) {
        const int r   = lane / 7;            // magic-mul
        const int col = lane - r * 7;
        const int* eA = edge_ids + (size_t)nA * (N_PATH * (L_PATH - 1));
        const int* eB = edge_ids + (size_t)nB * (N_PATH * (L_PATH - 1));
        int* dA = out_edges + (size_t)nA * (K_PATH * (L_PATH - 1));
        int* dB = out_edges + (size_t)nB * (K_PATH * (L_PATH - 1));
        const int s0 = wsrc[wv][0][r];
        const int s1 = wsrc[wv][1][r];
        __builtin_nontemporal_store(eA[s0 * 7 + col], dA + lane);
        __builtin_nontemporal_store(eB[s1 * 7 + col], dB + lane);
    }
}

extern "C" void kernel_launch(void* const* d_in, const int* in_sizes, int n_in,
                              void* d_out, int out_size, void* d_ws, size_t ws_size,
                              hipStream_t stream) {
    const int*   paths      = (const int*)  d_in[0];
    const int*   edge_ids   = (const int*)  d_in[1];
    const int*   rand_lens  = (const int*)  d_in[2];
    const float* centrality = (const float*)d_in[3];
    // d_in[4] is k_path (scalar, known == 8)

    int* out_paths = (int*)d_out;
    int* out_edges = out_paths + (size_t)N_NODE * K_PATH * L_PATH;

    // 4 waves/block x 2 nodes/wave = 8 nodes/block
    const int grid = N_NODE / 8;             // 12500, exact

    path_sampling_kernel<<<grid, 256, 0, stream>>>(
        paths, edge_ids, rand_lens, centrality, out_paths, out_edges);
}